// Round 5
// baseline (126.176 us; speedup 1.0000x reference)
//
#include <hip/hip_runtime.h>
#include <cmath>

// MoE router via 3-way bf16-split MFMA emulation of fp32 GEMM, compensated
// (TwoSum) accumulation. R5: NO LDS, NO BARRIERS — w3 (1.5 MB, L2/L1-resident)
// is pre-formatted into per-lane MFMA B-fragment layout and loaded straight
// into registers; each wave computes 32 tokens (2 A-tiles share each B-frag);
// x prefetched one chunk ahead in named registers. Corrections merged into
// the main accumulator (TwoSum folds every 4 chunks keep logit err ~1e-7).
//
// logits[T,64] = x[T,4096] @ w[64,4096]^T, sigmoid, top-8 on prob+bias,
// weights = p/sum*2.5. Outputs: weights[T,8] f32, then indices[T,8] as f32.

typedef float f32x4 __attribute__((ext_vector_type(4)));
typedef short s16x8 __attribute__((ext_vector_type(8)));

#define E_DIM 64
#define KC 32
#define CH_BYTES 12288   // 3 splits * 4 ntiles * 64 lanes * 16B
#define NPART 4
#define HI_OFF (2u << 20)   // partials start at 2 MB (w3 is 1.5 MB)

__device__ __forceinline__ unsigned short f2bf(float f) {
  unsigned u = __float_as_uint(f);
  u += 0x7fffu + ((u >> 16) & 1u);   // round-to-nearest-even
  return (unsigned short)(u >> 16);
}
__device__ __forceinline__ float bf2f(unsigned short s) {
  return __uint_as_float(((unsigned)s) << 16);
}

// ---- kernel W: split w into 3 bf16 planes, in per-lane B-fragment layout ----
// w3[c][s][n][lane]*16B ; lane holds expert e=n*16+(lane&15),
// k = c*32 + (lane>>4)*8 + j  (j=0..7 within the 16B slot).
__global__ __launch_bounds__(256) void split_w(
    const float* __restrict__ w, unsigned char* __restrict__ w3, int Hdim)
{
  const int kpr = Hdim >> 4;                      // 16-elem k-groups per row
  const int g = blockIdx.x * 256 + threadIdx.x;
  const int e = g / kpr;
  const int k0 = (g - e * kpr) * 16;
  if (e >= E_DIM) return;

  const float* src = w + (size_t)e * Hdim + k0;
  float f[16];
#pragma unroll
  for (int i = 0; i < 4; ++i) {
    float4 v = *(const float4*)(src + i * 4);
    f[i*4+0] = v.x; f[i*4+1] = v.y; f[i*4+2] = v.z; f[i*4+3] = v.w;
  }
  unsigned short hs[16], ms[16], ls[16];
#pragma unroll
  for (int i = 0; i < 16; ++i) {
    unsigned short h = f2bf(f[i]);
    float r1 = f[i] - bf2f(h);
    unsigned short m = f2bf(r1);
    float r2 = r1 - bf2f(m);
    hs[i] = h; ms[i] = m; ls[i] = f2bf(r2);
  }
  const int c  = k0 >> 5;                          // chunk of 32 k
  const int n  = e >> 4;                           // n-tile
  const int la = (e & 15) + (((k0 & 31) >> 3) << 4);  // lane of first 8 elems
  unsigned char* base = w3 + (size_t)c * CH_BYTES + n * 1024;

#define STORE_SPLIT(arr, s)                                              \
  do {                                                                   \
    s16x8 pa, pb;                                                        \
    _Pragma("unroll")                                                    \
    for (int j = 0; j < 8; ++j) { pa[j] = (short)arr[j]; pb[j] = (short)arr[8+j]; } \
    *(s16x8*)(base + (s)*4096 + la * 16)        = pa;                    \
    *(s16x8*)(base + (s)*4096 + (la + 16) * 16) = pb;                    \
  } while (0)

  STORE_SPLIT(hs, 0);
  STORE_SPLIT(ms, 1);
  STORE_SPLIT(ls, 2);
#undef STORE_SPLIT
}

// ---- kernel G: register-resident MFMA GEMM, no LDS, no barriers ----
__global__ __launch_bounds__(256, 2) void router_mfma(
    const float* __restrict__ x, const unsigned char* __restrict__ w3,
    const float* __restrict__ bias, float* __restrict__ outw,
    float* __restrict__ outi, float* __restrict__ hi_p,
    float* __restrict__ lo_p, int T, int Hdim)
{
  const int tid  = threadIdx.x;
  const int wid  = tid >> 6;
  const int lane = tid & 63;
  const int lc   = lane & 15;   // token row in tile / expert col / D col
  const int lq   = lane >> 4;   // k-slot group / D row group
  const int by   = blockIdx.y;
  const int nch  = Hdim / KC / gridDim.y;
  const int t0w  = blockIdx.x * 128 + wid * 32;

  const float* x0 = x + (size_t)(t0w + lc) * Hdim + (size_t)by * nch * KC + lq * 8;
  const float* x1 = x0 + (size_t)16 * Hdim;
  const unsigned char* wb = w3 + (size_t)by * nch * CH_BYTES + lane * 16;

  f32x4 acc[2][4];   // MFMA accumulator (main + corrections merged)
  f32x4 sum_[2][4];  // TwoSum hi
  f32x4 comp[2][4];  // TwoSum lo
#pragma unroll
  for (int t = 0; t < 2; ++t)
#pragma unroll
    for (int n = 0; n < 4; ++n) {
      acc[t][n] = (f32x4){0,0,0,0};
      sum_[t][n] = (f32x4){0,0,0,0};
      comp[t][n] = (f32x4){0,0,0,0};
    }

#define LOADB(c, B)                                                          \
  do {                                                                       \
    const unsigned char* p_ = wb + (size_t)(c) * CH_BYTES;                   \
    _Pragma("unroll")                                                        \
    for (int s = 0; s < 3; ++s) {                                            \
      const unsigned char* ps_ = p_ + s * 4096;                              \
      _Pragma("unroll")                                                      \
      for (int n = 0; n < 4; ++n)                                            \
        B[s*4+n] = *(const s16x8*)(ps_ + n * 1024);                          \
    }                                                                        \
  } while (0)

#define LOADX(c, X)                                                          \
  do {                                                                       \
    X[0] = *(const float4*)(x0 + (size_t)(c) * KC);                          \
    X[1] = *(const float4*)(x0 + (size_t)(c) * KC + 4);                      \
    X[2] = *(const float4*)(x1 + (size_t)(c) * KC);                          \
    X[3] = *(const float4*)(x1 + (size_t)(c) * KC + 4);                      \
  } while (0)

#define COMPUTE(X, B)                                                        \
  do {                                                                       \
    _Pragma("unroll")                                                        \
    for (int t = 0; t < 2; ++t) {                                            \
      float fv[8] = {X[t*2].x, X[t*2].y, X[t*2].z, X[t*2].w,                 \
                     X[t*2+1].x, X[t*2+1].y, X[t*2+1].z, X[t*2+1].w};        \
      s16x8 ah, am, al;                                                      \
      _Pragma("unroll")                                                      \
      for (int j = 0; j < 8; ++j) {                                          \
        unsigned short h_ = f2bf(fv[j]);                                     \
        float r1_ = fv[j] - bf2f(h_);                                        \
        unsigned short m_ = f2bf(r1_);                                       \
        float r2_ = r1_ - bf2f(m_);                                          \
        ah[j] = (short)h_; am[j] = (short)m_; al[j] = (short)f2bf(r2_);      \
      }                                                                      \
      _Pragma("unroll")                                                      \
      for (int n = 0; n < 4; ++n) {                                          \
        acc[t][n] = __builtin_amdgcn_mfma_f32_16x16x32_bf16(ah, B[n],   acc[t][n], 0,0,0); \
        acc[t][n] = __builtin_amdgcn_mfma_f32_16x16x32_bf16(ah, B[4+n], acc[t][n], 0,0,0); \
        acc[t][n] = __builtin_amdgcn_mfma_f32_16x16x32_bf16(am, B[n],   acc[t][n], 0,0,0); \
        acc[t][n] = __builtin_amdgcn_mfma_f32_16x16x32_bf16(ah, B[8+n], acc[t][n], 0,0,0); \
        acc[t][n] = __builtin_amdgcn_mfma_f32_16x16x32_bf16(am, B[4+n], acc[t][n], 0,0,0); \
        acc[t][n] = __builtin_amdgcn_mfma_f32_16x16x32_bf16(al, B[n],   acc[t][n], 0,0,0); \
      }                                                                      \
    }                                                                        \
  } while (0)

  // TwoSum fold: (sum_,comp) += acc exactly; acc reset. Adds/subs only.
#define FOLD()                                                               \
  do {                                                                       \
    _Pragma("unroll")                                                        \
    for (int t = 0; t < 2; ++t)                                              \
      _Pragma("unroll")                                                      \
      for (int n = 0; n < 4; ++n)                                            \
        _Pragma("unroll")                                                    \
        for (int r = 0; r < 4; ++r) {                                        \
          float a_ = acc[t][n][r];                                           \
          float s_ = sum_[t][n][r];                                          \
          float t_ = s_ + a_;                                                \
          float z_ = t_ - s_;                                                \
          comp[t][n][r] += (s_ - (t_ - z_)) + (a_ - z_);                     \
          sum_[t][n][r] = t_;                                                \
          acc[t][n][r] = 0.f;                                                \
        }                                                                    \
  } while (0)

  float4 XA[4], XB[4];
  LOADX(0, XA);

#pragma unroll 1
  for (int c = 0; c < nch; c += 2) {
    s16x8 BA[12];
    LOADB(c, BA);              // B first: MFMA's vmcnt leaves x-prefetch in flight
    LOADX(c + 1, XB);
    COMPUTE(XA, BA);
    s16x8 BB[12];
    LOADB(c + 1, BB);
    if (c + 2 < nch) LOADX(c + 2, XA);
    COMPUTE(XB, BB);
    if ((c & 2) == 2) FOLD();  // fold every 4 chunks (chain-4, matches R3)
  }
  FOLD();  // exact no-op if already folded; covers nch%4==2

  if (gridDim.y != 1) {
    // ---- partial mode: write (hi, lo) planes ----
#pragma unroll
    for (int t = 0; t < 2; ++t)
#pragma unroll
      for (int n = 0; n < 4; ++n)
#pragma unroll
        for (int r = 0; r < 4; ++r) {
          const int tok = t0w + t * 16 + lq * 4 + r;
          const size_t o = ((size_t)by * T + tok) * E_DIM + n * 16 + lc;
          hi_p[o] = sum_[t][n][r];
          lo_p[o] = comp[t][n][r];
        }
    return;
  }

  // ---- fused epilogue (fallback, gridDim.y==1) ----
  float bias_v[4];
#pragma unroll
  for (int n = 0; n < 4; ++n) bias_v[n] = bias[n * 16 + lc];

#pragma unroll
  for (int t = 0; t < 2; ++t) {
    float pr[4][4], bi[4][4];
#pragma unroll
    for (int n = 0; n < 4; ++n)
#pragma unroll
      for (int r = 0; r < 4; ++r) {
        float logit = sum_[t][n][r] + comp[t][n][r];
        float p = 1.0f / (1.0f + expf(-logit));
        pr[n][r] = p;
        bi[n][r] = p + bias_v[n];
      }
#pragma unroll
    for (int r = 0; r < 4; ++r) {
      float v0 = bi[0][r], v1 = bi[1][r], v2 = bi[2][r], v3 = bi[3][r];
      float p0 = pr[0][r], p1 = pr[1][r], p2 = pr[2][r], p3 = pr[3][r];
      float sum = 0.f, selp = 0.f;
      int seli = 0;
#pragma unroll
      for (int k = 0; k < 8; ++k) {
        float bv = v0; int bn = 0; float bp = p0;
        if (v1 > bv) { bv = v1; bn = 1; bp = p1; }
        if (v2 > bv) { bv = v2; bn = 2; bp = p2; }
        if (v3 > bv) { bv = v3; bn = 3; bp = p3; }
        int be = bn * 16 + lc;
#pragma unroll
        for (int off = 8; off >= 1; off >>= 1) {
          float ov = __shfl_xor(bv, off);
          float op = __shfl_xor(bp, off);
          int   oe = __shfl_xor(be, off);
          if (ov > bv || (ov == bv && oe < be)) { bv = ov; bp = op; be = oe; }
        }
        sum += bp;
        if (lc == k) { selp = bp; seli = be; }
        if (lc == (be & 15)) {
          int gsel = be >> 4;
          if      (gsel == 0) v0 = -1e30f;
          else if (gsel == 1) v1 = -1e30f;
          else if (gsel == 2) v2 = -1e30f;
          else                v3 = -1e30f;
        }
      }
      if (lc < 8) {
        const int tok = t0w + t * 16 + lq * 4 + r;
        outw[(size_t)tok * 8 + lc] = selp * 2.5f / (sum + 1e-20f);
        outi[(size_t)tok * 8 + lc] = (float)seli;
      }
    }
  }
}

// ---- kernel T: combine partials (TwoSum) + sigmoid + top-8 ----
__global__ __launch_bounds__(256) void router_topk(
    const float* __restrict__ hi_p, const float* __restrict__ lo_p,
    const float* __restrict__ bias, float* __restrict__ outw,
    float* __restrict__ outi, int T)
{
  const int lane = threadIdx.x & 63;
  const int t = blockIdx.x * 4 + (threadIdx.x >> 6);
  if (t >= T) return;

  float s = 0.f, c = 0.f, losum = 0.f;
#pragma unroll
  for (int p = 0; p < NPART; ++p) {
    const size_t o = ((size_t)p * T + t) * E_DIM + lane;
    float a = hi_p[o];
    float tt = s + a;
    float z = tt - s;
    c += (s - (tt - z)) + (a - z);
    s = tt;
    losum += lo_p[o];
  }
  const float logit = s + (c + losum);

  const float prob = 1.0f / (1.0f + expf(-logit));
  float v = prob + bias[lane];

  float sum = 0.f, selw = 0.f;
  int seli = 0;
#pragma unroll
  for (int k = 0; k < 8; ++k) {
    float rv = v;
    int   ri = lane;
#pragma unroll
    for (int off = 32; off > 0; off >>= 1) {
      float ov = __shfl_xor(rv, off);
      int   oi = __shfl_xor(ri, off);
      if (ov > rv || (ov == rv && oi < ri)) { rv = ov; ri = oi; }
    }
    float pwin = __shfl(prob, ri);
    sum += pwin;
    if (lane == k)  { selw = pwin; seli = ri; }
    if (lane == ri) v = -INFINITY;
  }

  if (lane < 8) {
    float scale = 2.5f / (sum + 1e-20f);
    outw[(size_t)t * 8 + lane] = selw * scale;
    outi[(size_t)t * 8 + lane] = (float)seli;
  }
}

extern "C" void kernel_launch(void* const* d_in, const int* in_sizes, int n_in,
                              void* d_out, int out_size, void* d_ws, size_t ws_size,
                              hipStream_t stream) {
  const float* x    = (const float*)d_in[0];
  const float* w    = (const float*)d_in[1];
  const float* bias = (const float*)d_in[2];

  const int E    = in_sizes[2];          // 64
  const int Hdim = in_sizes[1] / E;      // 4096
  const int T    = in_sizes[0] / Hdim;   // 16384

  unsigned char* ws = (unsigned char*)d_ws;
  unsigned char* w3 = ws;                      // 1.5 MB
  float* hi_p = (float*)(ws + HI_OFF);         // NPART*T*64 f32 = 16 MB
  float* lo_p = hi_p + (size_t)NPART * T * E_DIM;

  const size_t need = (size_t)HI_OFF + (size_t)2 * NPART * T * E_DIM * sizeof(float);
  const int nparts = (ws_size >= need) ? NPART : 1;

  const int nElemGroups = E * Hdim / 16;
  split_w<<<(nElemGroups + 255) / 256, 256, 0, stream>>>(w, w3, Hdim);

  float* outw = (float*)d_out;
  float* outi = outw + (size_t)T * 8;

  dim3 gridG(T / 128, nparts);
  router_mfma<<<gridG, 256, 0, stream>>>(x, w3, bias, outw, outi, hi_p, lo_p, T, Hdim);

  if (nparts != 1) {
    router_topk<<<(T + 3) / 4, 256, 0, stream>>>(hi_p, lo_p, bias, outw, outi, T);
  }
}

// Round 6
// 124.101 us; speedup vs baseline: 1.0167x; 1.0167x over previous
//
#include <hip/hip_runtime.h>
#include <cmath>

// MoE router via 3-way bf16-split MFMA emulation of fp32 GEMM, compensated
// (TwoSum) accumulation. R6: barrier-free register pipeline — BOTH B (w3,
// L2-resident, pre-formatted per-lane fragments) and x are prefetched one
// chunk ahead into named registers, so per-chunk waitcnt targets loads issued
// one full COMPUTE earlier (L2 latency hidden without LDS/barriers).
// x split uses round-half-up (+0x8000) + v_perm_b32 packing: 68 VALU / 8
// elems (was ~128), same 2^-24 error chain as RNE.
//
// logits[T,64] = x[T,4096] @ w[64,4096]^T, sigmoid, top-8 on prob+bias,
// weights = p/sum*2.5. Outputs: weights[T,8] f32, then indices[T,8] as f32.

typedef float f32x4 __attribute__((ext_vector_type(4)));
typedef short s16x8 __attribute__((ext_vector_type(8)));
typedef unsigned int u32;
typedef u32 u32x4 __attribute__((ext_vector_type(4)));

#define E_DIM 64
#define KC 32
#define CH_BYTES 12288   // 3 splits * 4 ntiles * 64 lanes * 16B
#define NPART 4
#define HI_OFF (2u << 20)   // partials start at 2 MB (w3 is 1.5 MB)

union V16 { u32x4 u; s16x8 s; };

__device__ __forceinline__ unsigned short f2bf(float f) {
  unsigned u = __float_as_uint(f);
  u += 0x7fffu + ((u >> 16) & 1u);   // round-to-nearest-even
  return (unsigned short)(u >> 16);
}
__device__ __forceinline__ float bf2f(unsigned short s) {
  return __uint_as_float(((unsigned)s) << 16);
}

// ---- kernel W: split w into 3 bf16 planes, in per-lane B-fragment layout ----
// w3[c][s][n][lane]*16B ; lane holds expert e=n*16+(lane&15),
// k = c*32 + (lane>>4)*8 + j  (j=0..7 within the 16B slot).
__global__ __launch_bounds__(256) void split_w(
    const float* __restrict__ w, unsigned char* __restrict__ w3, int Hdim)
{
  const int kpr = Hdim >> 4;                      // 16-elem k-groups per row
  const int g = blockIdx.x * 256 + threadIdx.x;
  const int e = g / kpr;
  const int k0 = (g - e * kpr) * 16;
  if (e >= E_DIM) return;

  const float* src = w + (size_t)e * Hdim + k0;
  float f[16];
#pragma unroll
  for (int i = 0; i < 4; ++i) {
    float4 v = *(const float4*)(src + i * 4);
    f[i*4+0] = v.x; f[i*4+1] = v.y; f[i*4+2] = v.z; f[i*4+3] = v.w;
  }
  unsigned short hs[16], ms[16], ls[16];
#pragma unroll
  for (int i = 0; i < 16; ++i) {
    unsigned short h = f2bf(f[i]);
    float r1 = f[i] - bf2f(h);
    unsigned short m = f2bf(r1);
    float r2 = r1 - bf2f(m);
    hs[i] = h; ms[i] = m; ls[i] = f2bf(r2);
  }
  const int c  = k0 >> 5;                          // chunk of 32 k
  const int n  = e >> 4;                           // n-tile
  const int la = (e & 15) + (((k0 & 31) >> 3) << 4);  // lane of first 8 elems
  unsigned char* base = w3 + (size_t)c * CH_BYTES + n * 1024;

#define STORE_SPLIT(arr, s)                                              \
  do {                                                                   \
    s16x8 pa, pb;                                                        \
    _Pragma("unroll")                                                    \
    for (int j = 0; j < 8; ++j) { pa[j] = (short)arr[j]; pb[j] = (short)arr[8+j]; } \
    *(s16x8*)(base + (s)*4096 + la * 16)        = pa;                    \
    *(s16x8*)(base + (s)*4096 + (la + 16) * 16) = pb;                    \
  } while (0)

  STORE_SPLIT(hs, 0);
  STORE_SPLIT(ms, 1);
  STORE_SPLIT(ls, 2);
#undef STORE_SPLIT
}

// ---- kernel G: register-pipelined MFMA GEMM, no LDS, no barriers ----
__global__ __launch_bounds__(256, 2) void router_mfma(
    const float* __restrict__ x, const unsigned char* __restrict__ w3,
    const float* __restrict__ bias, float* __restrict__ outw,
    float* __restrict__ outi, float* __restrict__ hi_p,
    float* __restrict__ lo_p, int T, int Hdim)
{
  const int tid  = threadIdx.x;
  const int wid  = tid >> 6;
  const int lane = tid & 63;
  const int lc   = lane & 15;   // token row in tile / expert col / D col
  const int lq   = lane >> 4;   // k-slot group / D row group
  const int by   = blockIdx.y;
  const int nch  = Hdim / KC / gridDim.y;
  const int t0w  = blockIdx.x * 128 + wid * 32;

  const float* x0 = x + (size_t)(t0w + lc) * Hdim + (size_t)by * nch * KC + lq * 8;
  const float* x1 = x0 + (size_t)16 * Hdim;
  const unsigned char* wb = w3 + (size_t)by * nch * CH_BYTES + lane * 16;

  f32x4 acc[2][4];   // MFMA accumulator (short chains, all 6 products)
  f32x4 sum_[2][4];  // TwoSum hi
  f32x4 comp[2][4];  // TwoSum lo
#pragma unroll
  for (int t = 0; t < 2; ++t)
#pragma unroll
    for (int n = 0; n < 4; ++n) {
      acc[t][n] = (f32x4){0,0,0,0};
      sum_[t][n] = (f32x4){0,0,0,0};
      comp[t][n] = (f32x4){0,0,0,0};
    }

#define LOADB(c, B)                                                          \
  do {                                                                       \
    const unsigned char* p_ = wb + (size_t)(c) * CH_BYTES;                   \
    _Pragma("unroll")                                                        \
    for (int s = 0; s < 3; ++s) {                                            \
      const unsigned char* ps_ = p_ + s * 4096;                              \
      _Pragma("unroll")                                                      \
      for (int n = 0; n < 4; ++n)                                            \
        B[s*4+n] = *(const s16x8*)(ps_ + n * 1024);                          \
    }                                                                        \
  } while (0)

#define LOADX(c, X)                                                          \
  do {                                                                       \
    X[0] = *(const float4*)(x0 + (size_t)(c) * KC);                          \
    X[1] = *(const float4*)(x0 + (size_t)(c) * KC + 4);                      \
    X[2] = *(const float4*)(x1 + (size_t)(c) * KC);                          \
    X[3] = *(const float4*)(x1 + (size_t)(c) * KC + 4);                      \
  } while (0)

  // round-half-up bf16 split + v_perm pack: f = h + m + l, err ~2^-24|f|.
#define SPLIT_PAIR(f0, f1, i, AHU, AMU, ALU)                                 \
  do {                                                                       \
    u32 u0_ = __float_as_uint(f0), u1_ = __float_as_uint(f1);                \
    u32 v0_ = u0_ + 0x8000u, v1_ = u1_ + 0x8000u;                            \
    AHU[i] = __builtin_amdgcn_perm(v1_, v0_, 0x07060302u);                   \
    float r0_ = (f0) - __uint_as_float(v0_ & 0xffff0000u);                   \
    float r1_ = (f1) - __uint_as_float(v1_ & 0xffff0000u);                   \
    u32 w0_ = __float_as_uint(r0_) + 0x8000u;                                \
    u32 w1_ = __float_as_uint(r1_) + 0x8000u;                                \
    AMU[i] = __builtin_amdgcn_perm(w1_, w0_, 0x07060302u);                   \
    float s0_ = r0_ - __uint_as_float(w0_ & 0xffff0000u);                    \
    float s1_ = r1_ - __uint_as_float(w1_ & 0xffff0000u);                    \
    u32 y0_ = __float_as_uint(s0_) + 0x8000u;                                \
    u32 y1_ = __float_as_uint(s1_) + 0x8000u;                                \
    ALU[i] = __builtin_amdgcn_perm(y1_, y0_, 0x07060302u);                   \
  } while (0)

#define COMPUTE(X, B)                                                        \
  do {                                                                       \
    _Pragma("unroll")                                                        \
    for (int t = 0; t < 2; ++t) {                                            \
      V16 ah_, am_, al_;                                                     \
      SPLIT_PAIR(X[t*2].x, X[t*2].y, 0, ah_.u, am_.u, al_.u);                \
      SPLIT_PAIR(X[t*2].z, X[t*2].w, 1, ah_.u, am_.u, al_.u);                \
      SPLIT_PAIR(X[t*2+1].x, X[t*2+1].y, 2, ah_.u, am_.u, al_.u);            \
      SPLIT_PAIR(X[t*2+1].z, X[t*2+1].w, 3, ah_.u, am_.u, al_.u);            \
      s16x8 ah = ah_.s, am = am_.s, al = al_.s;                              \
      __builtin_amdgcn_s_setprio(1);                                         \
      _Pragma("unroll")                                                      \
      for (int n = 0; n < 4; ++n) {                                          \
        acc[t][n] = __builtin_amdgcn_mfma_f32_16x16x32_bf16(ah, B[n],   acc[t][n], 0,0,0); \
        acc[t][n] = __builtin_amdgcn_mfma_f32_16x16x32_bf16(ah, B[4+n], acc[t][n], 0,0,0); \
        acc[t][n] = __builtin_amdgcn_mfma_f32_16x16x32_bf16(am, B[n],   acc[t][n], 0,0,0); \
        acc[t][n] = __builtin_amdgcn_mfma_f32_16x16x32_bf16(ah, B[8+n], acc[t][n], 0,0,0); \
        acc[t][n] = __builtin_amdgcn_mfma_f32_16x16x32_bf16(am, B[4+n], acc[t][n], 0,0,0); \
        acc[t][n] = __builtin_amdgcn_mfma_f32_16x16x32_bf16(al, B[n],   acc[t][n], 0,0,0); \
      }                                                                      \
      __builtin_amdgcn_s_setprio(0);                                         \
    }                                                                        \
  } while (0)

  // TwoSum fold: (sum_,comp) += acc exactly; acc reset. Adds/subs only.
#define FOLD()                                                               \
  do {                                                                       \
    _Pragma("unroll")                                                        \
    for (int t = 0; t < 2; ++t)                                              \
      _Pragma("unroll")                                                      \
      for (int n = 0; n < 4; ++n)                                            \
        _Pragma("unroll")                                                    \
        for (int r = 0; r < 4; ++r) {                                        \
          float a_ = acc[t][n][r];                                           \
          float s_ = sum_[t][n][r];                                          \
          float t_ = s_ + a_;                                                \
          float z_ = t_ - s_;                                                \
          comp[t][n][r] += (s_ - (t_ - z_)) + (a_ - z_);                     \
          sum_[t][n][r] = t_;                                                \
          acc[t][n][r] = 0.f;                                                \
        }                                                                    \
  } while (0)

  float4 XA[4], XB[4];
  s16x8 BA[12], BB[12];

  LOADB(0, BA);
  LOADX(0, XA);

#pragma unroll 1
  for (int c = 0; c < nch; c += 2) {
    LOADB(c + 1, BB);            // prefetch next chunk (B then x)
    LOADX(c + 1, XB);
    COMPUTE(XA, BA);             // waits only on loads issued one COMPUTE ago
    if (c + 2 < nch) { LOADB(c + 2, BA); LOADX(c + 2, XA); }
    COMPUTE(XB, BB);
    if ((c & 2) == 2) FOLD();    // fold every 4 chunks (chain-4)
  }
  FOLD();  // exact no-op if already folded; covers tail group

  if (gridDim.y != 1) {
    // ---- partial mode: write (hi, lo) planes ----
#pragma unroll
    for (int t = 0; t < 2; ++t)
#pragma unroll
      for (int n = 0; n < 4; ++n)
#pragma unroll
        for (int r = 0; r < 4; ++r) {
          const int tok = t0w + t * 16 + lq * 4 + r;
          const size_t o = ((size_t)by * T + tok) * E_DIM + n * 16 + lc;
          hi_p[o] = sum_[t][n][r];
          lo_p[o] = comp[t][n][r];
        }
    return;
  }

  // ---- fused epilogue (fallback, gridDim.y==1) ----
  float bias_v[4];
#pragma unroll
  for (int n = 0; n < 4; ++n) bias_v[n] = bias[n * 16 + lc];

#pragma unroll
  for (int t = 0; t < 2; ++t) {
    float pr[4][4], bi[4][4];
#pragma unroll
    for (int n = 0; n < 4; ++n)
#pragma unroll
      for (int r = 0; r < 4; ++r) {
        float logit = sum_[t][n][r] + comp[t][n][r];
        float p = 1.0f / (1.0f + expf(-logit));
        pr[n][r] = p;
        bi[n][r] = p + bias_v[n];
      }
#pragma unroll
    for (int r = 0; r < 4; ++r) {
      float v0 = bi[0][r], v1 = bi[1][r], v2 = bi[2][r], v3 = bi[3][r];
      float p0 = pr[0][r], p1 = pr[1][r], p2 = pr[2][r], p3 = pr[3][r];
      float sum = 0.f, selp = 0.f;
      int seli = 0;
#pragma unroll
      for (int k = 0; k < 8; ++k) {
        float bv = v0; int bn = 0; float bp = p0;
        if (v1 > bv) { bv = v1; bn = 1; bp = p1; }
        if (v2 > bv) { bv = v2; bn = 2; bp = p2; }
        if (v3 > bv) { bv = v3; bn = 3; bp = p3; }
        int be = bn * 16 + lc;
#pragma unroll
        for (int off = 8; off >= 1; off >>= 1) {
          float ov = __shfl_xor(bv, off);
          float op = __shfl_xor(bp, off);
          int   oe = __shfl_xor(be, off);
          if (ov > bv || (ov == bv && oe < be)) { bv = ov; bp = op; be = oe; }
        }
        sum += bp;
        if (lc == k) { selp = bp; seli = be; }
        if (lc == (be & 15)) {
          int gsel = be >> 4;
          if      (gsel == 0) v0 = -1e30f;
          else if (gsel == 1) v1 = -1e30f;
          else if (gsel == 2) v2 = -1e30f;
          else                v3 = -1e30f;
        }
      }
      if (lc < 8) {
        const int tok = t0w + t * 16 + lq * 4 + r;
        outw[(size_t)tok * 8 + lc] = selp * 2.5f / (sum + 1e-20f);
        outi[(size_t)tok * 8 + lc] = (float)seli;
      }
    }
  }
}

// ---- kernel T: combine partials (TwoSum) + sigmoid + top-8 ----
__global__ __launch_bounds__(256) void router_topk(
    const float* __restrict__ hi_p, const float* __restrict__ lo_p,
    const float* __restrict__ bias, float* __restrict__ outw,
    float* __restrict__ outi, int T)
{
  const int lane = threadIdx.x & 63;
  const int t = blockIdx.x * 4 + (threadIdx.x >> 6);
  if (t >= T) return;

  float s = 0.f, c = 0.f, losum = 0.f;
#pragma unroll
  for (int p = 0; p < NPART; ++p) {
    const size_t o = ((size_t)p * T + t) * E_DIM + lane;
    float a = hi_p[o];
    float tt = s + a;
    float z = tt - s;
    c += (s - (tt - z)) + (a - z);
    s = tt;
    losum += lo_p[o];
  }
  const float logit = s + (c + losum);

  const float prob = 1.0f / (1.0f + expf(-logit));
  float v = prob + bias[lane];

  float sum = 0.f, selw = 0.f;
  int seli = 0;
#pragma unroll
  for (int k = 0; k < 8; ++k) {
    float rv = v;
    int   ri = lane;
#pragma unroll
    for (int off = 32; off > 0; off >>= 1) {
      float ov = __shfl_xor(rv, off);
      int   oi = __shfl_xor(ri, off);
      if (ov > rv || (ov == rv && oi < ri)) { rv = ov; ri = oi; }
    }
    float pwin = __shfl(prob, ri);
    sum += pwin;
    if (lane == k)  { selw = pwin; seli = ri; }
    if (lane == ri) v = -INFINITY;
  }

  if (lane < 8) {
    float scale = 2.5f / (sum + 1e-20f);
    outw[(size_t)t * 8 + lane] = selw * scale;
    outi[(size_t)t * 8 + lane] = (float)seli;
  }
}

extern "C" void kernel_launch(void* const* d_in, const int* in_sizes, int n_in,
                              void* d_out, int out_size, void* d_ws, size_t ws_size,
                              hipStream_t stream) {
  const float* x    = (const float*)d_in[0];
  const float* w    = (const float*)d_in[1];
  const float* bias = (const float*)d_in[2];

  const int E    = in_sizes[2];          // 64
  const int Hdim = in_sizes[1] / E;      // 4096
  const int T    = in_sizes[0] / Hdim;   // 16384

  unsigned char* ws = (unsigned char*)d_ws;
  unsigned char* w3 = ws;                      // 1.5 MB
  float* hi_p = (float*)(ws + HI_OFF);         // NPART*T*64 f32 = 16 MB
  float* lo_p = hi_p + (size_t)NPART * T * E_DIM;

  const size_t need = (size_t)HI_OFF + (size_t)2 * NPART * T * E_DIM * sizeof(float);
  const int nparts = (ws_size >= need) ? NPART : 1;

  const int nElemGroups = E * Hdim / 16;
  split_w<<<(nElemGroups + 255) / 256, 256, 0, stream>>>(w, w3, Hdim);

  float* outw = (float*)d_out;
  float* outi = outw + (size_t)T * 8;

  dim3 gridG(T / 128, nparts);
  router_mfma<<<gridG, 256, 0, stream>>>(x, w3, bias, outw, outi, hi_p, lo_p, T, Hdim);

  if (nparts != 1) {
    router_topk<<<(T + 3) / 4, 256, 0, stream>>>(hi_p, lo_p, bias, outw, outi, T);
  }
}

// Round 7
// 122.857 us; speedup vs baseline: 1.0270x; 1.0101x over previous
//
#include <hip/hip_runtime.h>
#include <cmath>

// MoE router via 3-way bf16-split MFMA emulation of fp32 GEMM, compensated
// (TwoSum) accumulation. R7: the R6 register pipeline was DISCARDED by the
// compiler (VGPR=108 == acc state only; loads sunk to use). Fix: 1-wave
// blocks (64thr, 32 tok/wave, grid (T/32)x4 = 2048 = 8 waves/CU at <=256
// VGPR) + sched_barrier(0) fences pinning a half-chunk-phase pipeline:
// B ring depth 1 unit (~650cyc > L2 300), X depth 2 chunks (~2000cyc > HBM
// 900). 64KB/CU x-bytes in flight -> HBM-bound (floor 43us).
//
// logits[T,64] = x[T,4096] @ w[64,4096]^T, sigmoid, top-8 on prob+bias,
// weights = p/sum*2.5. Outputs: weights[T,8] f32, then indices[T,8] as f32.

typedef float f32x4 __attribute__((ext_vector_type(4)));
typedef short s16x8 __attribute__((ext_vector_type(8)));
typedef unsigned int u32;
typedef u32 u32x4 __attribute__((ext_vector_type(4)));

#define E_DIM 64
#define KC 32
#define CH_BYTES 12288   // 3 splits * 4 ntiles * 64 lanes * 16B
#define NPART 4
#define HI_OFF (2u << 20)   // partials start at 2 MB (w3 is 1.5 MB)

union V16 { u32x4 u; s16x8 s; };

__device__ __forceinline__ unsigned short f2bf(float f) {
  unsigned u = __float_as_uint(f);
  u += 0x7fffu + ((u >> 16) & 1u);   // round-to-nearest-even
  return (unsigned short)(u >> 16);
}
__device__ __forceinline__ float bf2f(unsigned short s) {
  return __uint_as_float(((unsigned)s) << 16);
}

// ---- kernel W: split w into 3 bf16 planes, in per-lane B-fragment layout ----
// w3[c][s][n][lane]*16B ; lane holds expert e=n*16+(lane&15),
// k = c*32 + (lane>>4)*8 + j  (j=0..7 within the 16B slot).
__global__ __launch_bounds__(256) void split_w(
    const float* __restrict__ w, unsigned char* __restrict__ w3, int Hdim)
{
  const int kpr = Hdim >> 4;                      // 16-elem k-groups per row
  const int g = blockIdx.x * 256 + threadIdx.x;
  const int e = g / kpr;
  const int k0 = (g - e * kpr) * 16;
  if (e >= E_DIM) return;

  const float* src = w + (size_t)e * Hdim + k0;
  float f[16];
#pragma unroll
  for (int i = 0; i < 4; ++i) {
    float4 v = *(const float4*)(src + i * 4);
    f[i*4+0] = v.x; f[i*4+1] = v.y; f[i*4+2] = v.z; f[i*4+3] = v.w;
  }
  unsigned short hs[16], ms[16], ls[16];
#pragma unroll
  for (int i = 0; i < 16; ++i) {
    unsigned short h = f2bf(f[i]);
    float r1 = f[i] - bf2f(h);
    unsigned short m = f2bf(r1);
    float r2 = r1 - bf2f(m);
    hs[i] = h; ms[i] = m; ls[i] = f2bf(r2);
  }
  const int c  = k0 >> 5;                          // chunk of 32 k
  const int n  = e >> 4;                           // n-tile
  const int la = (e & 15) + (((k0 & 31) >> 3) << 4);  // lane of first 8 elems
  unsigned char* base = w3 + (size_t)c * CH_BYTES + n * 1024;

#define STORE_SPLIT(arr, s)                                              \
  do {                                                                   \
    s16x8 pa, pb;                                                        \
    _Pragma("unroll")                                                    \
    for (int j = 0; j < 8; ++j) { pa[j] = (short)arr[j]; pb[j] = (short)arr[8+j]; } \
    *(s16x8*)(base + (s)*4096 + la * 16)        = pa;                    \
    *(s16x8*)(base + (s)*4096 + (la + 16) * 16) = pb;                    \
  } while (0)

  STORE_SPLIT(hs, 0);
  STORE_SPLIT(ms, 1);
  STORE_SPLIT(ls, 2);
#undef STORE_SPLIT
}

// ---- kernel G: 1-wave blocks, sched_barrier-pinned register pipeline ----
__global__ __launch_bounds__(64, 2) void router_mfma(
    const float* __restrict__ x, const unsigned char* __restrict__ w3,
    const float* __restrict__ bias, float* __restrict__ outw,
    float* __restrict__ outi, float* __restrict__ hi_p,
    float* __restrict__ lo_p, int T, int Hdim)
{
  const int lane = threadIdx.x;   // 64-thread block = 1 wave
  const int lc   = lane & 15;     // token row in tile / expert col / D col
  const int lq   = lane >> 4;     // k-slot group / D row group
  const int by   = blockIdx.y;
  const int nch  = Hdim / KC / gridDim.y;   // 32 (or 128 in fallback)
  const int t0w  = blockIdx.x * 32;

  const float* x0 = x + (size_t)(t0w + lc) * Hdim + (size_t)by * nch * KC + lq * 8;
  const float* x1 = x0 + (size_t)16 * Hdim;
  const unsigned char* wb = w3 + (size_t)by * nch * CH_BYTES + lane * 16;

  f32x4 acc[2][4];   // MFMA accumulator (24-MFMA chains between folds)
  f32x4 sum_[2][4];  // TwoSum hi
  f32x4 comp[2][4];  // TwoSum lo
#pragma unroll
  for (int t = 0; t < 2; ++t)
#pragma unroll
    for (int n = 0; n < 4; ++n) {
      acc[t][n] = (f32x4){0,0,0,0};
      sum_[t][n] = (f32x4){0,0,0,0};
      comp[t][n] = (f32x4){0,0,0,0};
    }

#define SB() __builtin_amdgcn_sched_barrier(0)

  // load one half-chunk B unit: splits s=0..2, n-tiles {2h, 2h+1}
#define LOADB_H(c, h, B)                                                     \
  do {                                                                       \
    const unsigned char* p_ = wb + (size_t)(c) * CH_BYTES + (h) * 2048;      \
    _Pragma("unroll")                                                        \
    for (int s = 0; s < 3; ++s)                                              \
      _Pragma("unroll")                                                      \
      for (int j = 0; j < 2; ++j)                                            \
        B[s*2+j] = *(const s16x8*)(p_ + s * 4096 + j * 1024);                \
  } while (0)

#define LOADX(c, X)                                                          \
  do {                                                                       \
    X[0] = *(const float4*)(x0 + (size_t)(c) * KC);                          \
    X[1] = *(const float4*)(x0 + (size_t)(c) * KC + 4);                      \
    X[2] = *(const float4*)(x1 + (size_t)(c) * KC);                          \
    X[3] = *(const float4*)(x1 + (size_t)(c) * KC + 4);                      \
  } while (0)

  // round-half-up bf16 split + v_perm pack: f = h + m + l, err ~2^-24|f|.
#define SPLIT_PAIR(f0, f1, i, AHU, AMU, ALU)                                 \
  do {                                                                       \
    u32 u0_ = __float_as_uint(f0), u1_ = __float_as_uint(f1);                \
    u32 v0_ = u0_ + 0x8000u, v1_ = u1_ + 0x8000u;                            \
    AHU[i] = __builtin_amdgcn_perm(v1_, v0_, 0x07060302u);                   \
    float r0_ = (f0) - __uint_as_float(v0_ & 0xffff0000u);                   \
    float r1_ = (f1) - __uint_as_float(v1_ & 0xffff0000u);                   \
    u32 w0_ = __float_as_uint(r0_) + 0x8000u;                                \
    u32 w1_ = __float_as_uint(r1_) + 0x8000u;                                \
    AMU[i] = __builtin_amdgcn_perm(w1_, w0_, 0x07060302u);                   \
    float s0_ = r0_ - __uint_as_float(w0_ & 0xffff0000u);                    \
    float s1_ = r1_ - __uint_as_float(w1_ & 0xffff0000u);                    \
    u32 y0_ = __float_as_uint(s0_) + 0x8000u;                                \
    u32 y1_ = __float_as_uint(s1_) + 0x8000u;                                \
    ALU[i] = __builtin_amdgcn_perm(y1_, y0_, 0x07060302u);                   \
  } while (0)

#define CONVERT(X)                                                           \
  do {                                                                       \
    _Pragma("unroll")                                                        \
    for (int t = 0; t < 2; ++t) {                                            \
      V16 ah_, am_, al_;                                                     \
      SPLIT_PAIR(X[t*2].x, X[t*2].y, 0, ah_.u, am_.u, al_.u);                \
      SPLIT_PAIR(X[t*2].z, X[t*2].w, 1, ah_.u, am_.u, al_.u);                \
      SPLIT_PAIR(X[t*2+1].x, X[t*2+1].y, 2, ah_.u, am_.u, al_.u);            \
      SPLIT_PAIR(X[t*2+1].z, X[t*2+1].w, 3, ah_.u, am_.u, al_.u);            \
      Aah[t] = ah_.s; Aam[t] = am_.s; Aal[t] = al_.s;                        \
    }                                                                        \
  } while (0)

  // 24 MFMAs, product-major so the 4 acc chains interleave (no dep stalls).
  // B[0..1]=h-plane n={2h,2h+1}, B[2..3]=m-plane, B[4..5]=l-plane.
#define COMPUTE_HALF(B, h)                                                   \
  do {                                                                       \
    __builtin_amdgcn_s_setprio(1);                                           \
    _Pragma("unroll")                                                        \
    for (int p = 0; p < 6; ++p)                                              \
      _Pragma("unroll")                                                      \
      for (int t = 0; t < 2; ++t)                                            \
        _Pragma("unroll")                                                    \
        for (int j = 0; j < 2; ++j) {                                        \
          const s16x8 a_ = (p==0||p==2||p==5) ? Aah[t]                       \
                         : (p==1||p==4)       ? Aam[t] : Aal[t];             \
          const s16x8 b_ = (p==0||p==1||p==3) ? B[j]                         \
                         : (p==2||p==4)       ? B[2+j] : B[4+j];             \
          acc[t][2*(h)+j] =                                                  \
            __builtin_amdgcn_mfma_f32_16x16x32_bf16(a_, b_, acc[t][2*(h)+j], 0,0,0); \
        }                                                                    \
    __builtin_amdgcn_s_setprio(0);                                           \
  } while (0)

  // TwoSum fold: (sum_,comp) += acc exactly; acc reset. Adds/subs only.
#define FOLD()                                                               \
  do {                                                                       \
    _Pragma("unroll")                                                        \
    for (int t = 0; t < 2; ++t)                                              \
      _Pragma("unroll")                                                      \
      for (int n = 0; n < 4; ++n)                                            \
        _Pragma("unroll")                                                    \
        for (int r = 0; r < 4; ++r) {                                        \
          float a_ = acc[t][n][r];                                           \
          float s_ = sum_[t][n][r];                                          \
          float t_ = s_ + a_;                                                \
          float z_ = t_ - s_;                                                \
          comp[t][n][r] += (s_ - (t_ - z_)) + (a_ - z_);                     \
          sum_[t][n][r] = t_;                                                \
          acc[t][n][r] = 0.f;                                                \
        }                                                                    \
  } while (0)

  // One 2-chunk sub-iteration of the pinned pipeline.
#define SUBITER(ca, XC0, XC1, XN0, XN1)                                      \
  do {                                                                       \
    const int cp2 = ((ca) + 2 < nch) ? (ca) + 2 : 0;                         \
    const int cp3 = ((ca) + 3 < nch) ? (ca) + 3 : 0;                         \
    LOADX(cp2, XN0);                                                         \
    SB();                                                                    \
    CONVERT(XC0);                                                            \
    COMPUTE_HALF(B0, 0);                                                     \
    SB();                                                                    \
    LOADB_H((ca) + 1, 0, B0);                                                \
    SB();                                                                    \
    COMPUTE_HALF(B1, 1);                                                     \
    SB();                                                                    \
    LOADB_H((ca) + 1, 1, B1);                                                \
    LOADX(cp3, XN1);                                                         \
    SB();                                                                    \
    CONVERT(XC1);                                                            \
    COMPUTE_HALF(B0, 0);                                                     \
    SB();                                                                    \
    LOADB_H(cp2, 0, B0);                                                     \
    SB();                                                                    \
    COMPUTE_HALF(B1, 1);                                                     \
    SB();                                                                    \
    LOADB_H(cp2, 1, B1);                                                     \
    SB();                                                                    \
  } while (0)

  float4 X0[4], X1[4], X2[4], X3[4];
  s16x8 B0[6], B1[6];
  s16x8 Aah[2], Aam[2], Aal[2];

  LOADB_H(0, 0, B0);
  LOADB_H(0, 1, B1);
  LOADX(0, X0);
  LOADX(1, X1);

#pragma unroll 1
  for (int c = 0; c < nch; c += 4) {
    SUBITER(c,     X0, X1, X2, X3);
    SUBITER(c + 2, X2, X3, X0, X1);
    FOLD();   // every 4 chunks -> 24-MFMA chains (matches R4/R6 precision)
  }

  if (gridDim.y != 1) {
    // ---- partial mode: write (hi, lo) planes ----
#pragma unroll
    for (int t = 0; t < 2; ++t)
#pragma unroll
      for (int n = 0; n < 4; ++n)
#pragma unroll
        for (int r = 0; r < 4; ++r) {
          const int tok = t0w + t * 16 + lq * 4 + r;
          const size_t o = ((size_t)by * T + tok) * E_DIM + n * 16 + lc;
          hi_p[o] = sum_[t][n][r];
          lo_p[o] = comp[t][n][r];
        }
    return;
  }

  // ---- fused epilogue (fallback, gridDim.y==1) ----
  float bias_v[4];
#pragma unroll
  for (int n = 0; n < 4; ++n) bias_v[n] = bias[n * 16 + lc];

#pragma unroll
  for (int t = 0; t < 2; ++t) {
    float pr[4][4], bi[4][4];
#pragma unroll
    for (int n = 0; n < 4; ++n)
#pragma unroll
      for (int r = 0; r < 4; ++r) {
        float logit = sum_[t][n][r] + comp[t][n][r];
        float p = 1.0f / (1.0f + expf(-logit));
        pr[n][r] = p;
        bi[n][r] = p + bias_v[n];
      }
#pragma unroll
    for (int r = 0; r < 4; ++r) {
      float v0 = bi[0][r], v1 = bi[1][r], v2 = bi[2][r], v3 = bi[3][r];
      float p0 = pr[0][r], p1 = pr[1][r], p2 = pr[2][r], p3 = pr[3][r];
      float sum = 0.f, selp = 0.f;
      int seli = 0;
#pragma unroll
      for (int k = 0; k < 8; ++k) {
        float bv = v0; int bn = 0; float bp = p0;
        if (v1 > bv) { bv = v1; bn = 1; bp = p1; }
        if (v2 > bv) { bv = v2; bn = 2; bp = p2; }
        if (v3 > bv) { bv = v3; bn = 3; bp = p3; }
        int be = bn * 16 + lc;
#pragma unroll
        for (int off = 8; off >= 1; off >>= 1) {
          float ov = __shfl_xor(bv, off);
          float op = __shfl_xor(bp, off);
          int   oe = __shfl_xor(be, off);
          if (ov > bv || (ov == bv && oe < be)) { bv = ov; bp = op; be = oe; }
        }
        sum += bp;
        if (lc == k) { selp = bp; seli = be; }
        if (lc == (be & 15)) {
          int gsel = be >> 4;
          if      (gsel == 0) v0 = -1e30f;
          else if (gsel == 1) v1 = -1e30f;
          else if (gsel == 2) v2 = -1e30f;
          else                v3 = -1e30f;
        }
      }
      if (lc < 8) {
        const int tok = t0w + t * 16 + lq * 4 + r;
        outw[(size_t)tok * 8 + lc] = selp * 2.5f / (sum + 1e-20f);
        outi[(size_t)tok * 8 + lc] = (float)seli;
      }
    }
  }
}

// ---- kernel T: combine partials (TwoSum) + sigmoid + top-8 ----
__global__ __launch_bounds__(256) void router_topk(
    const float* __restrict__ hi_p, const float* __restrict__ lo_p,
    const float* __restrict__ bias, float* __restrict__ outw,
    float* __restrict__ outi, int T)
{
  const int lane = threadIdx.x & 63;
  const int t = blockIdx.x * 4 + (threadIdx.x >> 6);
  if (t >= T) return;

  float s = 0.f, c = 0.f, losum = 0.f;
#pragma unroll
  for (int p = 0; p < NPART; ++p) {
    const size_t o = ((size_t)p * T + t) * E_DIM + lane;
    float a = hi_p[o];
    float tt = s + a;
    float z = tt - s;
    c += (s - (tt - z)) + (a - z);
    s = tt;
    losum += lo_p[o];
  }
  const float logit = s + (c + losum);

  const float prob = 1.0f / (1.0f + expf(-logit));
  float v = prob + bias[lane];

  float sum = 0.f, selw = 0.f;
  int seli = 0;
#pragma unroll
  for (int k = 0; k < 8; ++k) {
    float rv = v;
    int   ri = lane;
#pragma unroll
    for (int off = 32; off > 0; off >>= 1) {
      float ov = __shfl_xor(rv, off);
      int   oi = __shfl_xor(ri, off);
      if (ov > rv || (ov == rv && oi < ri)) { rv = ov; ri = oi; }
    }
    float pwin = __shfl(prob, ri);
    sum += pwin;
    if (lane == k)  { selw = pwin; seli = ri; }
    if (lane == ri) v = -INFINITY;
  }

  if (lane < 8) {
    float scale = 2.5f / (sum + 1e-20f);
    outw[(size_t)t * 8 + lane] = selw * scale;
    outi[(size_t)t * 8 + lane] = (float)seli;
  }
}

extern "C" void kernel_launch(void* const* d_in, const int* in_sizes, int n_in,
                              void* d_out, int out_size, void* d_ws, size_t ws_size,
                              hipStream_t stream) {
  const float* x    = (const float*)d_in[0];
  const float* w    = (const float*)d_in[1];
  const float* bias = (const float*)d_in[2];

  const int E    = in_sizes[2];          // 64
  const int Hdim = in_sizes[1] / E;      // 4096
  const int T    = in_sizes[0] / Hdim;   // 16384

  unsigned char* ws = (unsigned char*)d_ws;
  unsigned char* w3 = ws;                      // 1.5 MB
  float* hi_p = (float*)(ws + HI_OFF);         // NPART*T*64 f32 = 16 MB
  float* lo_p = hi_p + (size_t)NPART * T * E_DIM;

  const size_t need = (size_t)HI_OFF + (size_t)2 * NPART * T * E_DIM * sizeof(float);
  const int nparts = (ws_size >= need) ? NPART : 1;

  const int nElemGroups = E * Hdim / 16;
  split_w<<<(nElemGroups + 255) / 256, 256, 0, stream>>>(w, w3, Hdim);

  float* outw = (float*)d_out;
  float* outi = outw + (size_t)T * 8;

  dim3 gridG(T / 32, nparts);
  router_mfma<<<gridG, 64, 0, stream>>>(x, w3, bias, outw, outi, hi_p, lo_p, T, Hdim);

  if (nparts != 1) {
    router_topk<<<(T + 3) / 4, 256, 0, stream>>>(hi_p, lo_p, bias, outw, outi, T);
  }
}

// Round 8
// 112.269 us; speedup vs baseline: 1.1239x; 1.0943x over previous
//
#include <hip/hip_runtime.h>
#include <cmath>

// MoE router via 3-way bf16-split MFMA emulation of fp32 GEMM, compensated
// (TwoSum) accumulation. R8: occupancy + counted-vmcnt synthesis.
//  - 16-token waves (acc state 48 VGPR), 4-wave/256-thr blocks (64 tok),
//    grid (T/64)x4 = 1024 blocks -> 12-16 waves/CU (R3->R7 showed perf
//    tracks waves/CU, not pipeline depth).
//  - B staged in LDS (2x12KB dbuf, global_load_lds) -> B L2 traffic per-block.
//  - Raw s_barrier + s_waitcnt vmcnt(2): stage (L2-resident, issued a full
//    iter earlier) drains free; X HBM prefetch (4 named reg buffers, depth 2
//    iters) SURVIVES the barrier -- fixes both R4's vmcnt(0) drain and the
//    R5-R7 in-order-queue flaw.
//
// logits[T,64] = x[T,4096] @ w[64,4096]^T, sigmoid, top-8 on prob+bias,
// weights = p/sum*2.5. Outputs: weights[T,8] f32, then indices[T,8] as f32.

typedef float f32x4 __attribute__((ext_vector_type(4)));
typedef short s16x8 __attribute__((ext_vector_type(8)));
typedef unsigned int u32;
typedef u32 u32x4 __attribute__((ext_vector_type(4)));

#define E_DIM 64
#define KC 32
#define CH_BYTES 12288   // 3 splits * 4 ntiles * 64 lanes * 16B
#define NPART 4
#define HI_OFF (2u << 20)   // partials start at 2 MB (w3 is 1.5 MB)

union V16 { u32x4 u; s16x8 s; };

__device__ __forceinline__ unsigned short f2bf(float f) {
  unsigned u = __float_as_uint(f);
  u += 0x7fffu + ((u >> 16) & 1u);   // round-to-nearest-even
  return (unsigned short)(u >> 16);
}
__device__ __forceinline__ float bf2f(unsigned short s) {
  return __uint_as_float(((unsigned)s) << 16);
}

// ---- kernel W: split w into 3 bf16 planes, in per-lane B-fragment layout ----
// w3[c][s][n][lane]*16B ; lane holds expert e=n*16+(lane&15),
// k = c*32 + (lane>>4)*8 + j  (j=0..7 within the 16B slot).
__global__ __launch_bounds__(256) void split_w(
    const float* __restrict__ w, unsigned char* __restrict__ w3, int Hdim)
{
  const int kpr = Hdim >> 4;                      // 16-elem k-groups per row
  const int g = blockIdx.x * 256 + threadIdx.x;
  const int e = g / kpr;
  const int k0 = (g - e * kpr) * 16;
  if (e >= E_DIM) return;

  const float* src = w + (size_t)e * Hdim + k0;
  float f[16];
#pragma unroll
  for (int i = 0; i < 4; ++i) {
    float4 v = *(const float4*)(src + i * 4);
    f[i*4+0] = v.x; f[i*4+1] = v.y; f[i*4+2] = v.z; f[i*4+3] = v.w;
  }
  unsigned short hs[16], ms[16], ls[16];
#pragma unroll
  for (int i = 0; i < 16; ++i) {
    unsigned short h = f2bf(f[i]);
    float r1 = f[i] - bf2f(h);
    unsigned short m = f2bf(r1);
    float r2 = r1 - bf2f(m);
    hs[i] = h; ms[i] = m; ls[i] = f2bf(r2);
  }
  const int c  = k0 >> 5;                          // chunk of 32 k
  const int n  = e >> 4;                           // n-tile
  const int la = (e & 15) + (((k0 & 31) >> 3) << 4);  // lane of first 8 elems
  unsigned char* base = w3 + (size_t)c * CH_BYTES + n * 1024;

#define STORE_SPLIT(arr, s)                                              \
  do {                                                                   \
    s16x8 pa, pb;                                                        \
    _Pragma("unroll")                                                    \
    for (int j = 0; j < 8; ++j) { pa[j] = (short)arr[j]; pb[j] = (short)arr[8+j]; } \
    *(s16x8*)(base + (s)*4096 + la * 16)        = pa;                    \
    *(s16x8*)(base + (s)*4096 + (la + 16) * 16) = pb;                    \
  } while (0)

  STORE_SPLIT(hs, 0);
  STORE_SPLIT(ms, 1);
  STORE_SPLIT(ls, 2);
#undef STORE_SPLIT
}

// ---- kernel G: LDS-B + counted-vmcnt pipelined MFMA GEMM ----
__global__ __launch_bounds__(256, 3) void router_mfma(
    const float* __restrict__ x, const unsigned char* __restrict__ w3,
    const float* __restrict__ bias, float* __restrict__ outw,
    float* __restrict__ outi, float* __restrict__ hi_p,
    float* __restrict__ lo_p, int T, int Hdim)
{
  __shared__ __align__(16) unsigned char lds[2][CH_BYTES];  // 24 KB

  const int tid  = threadIdx.x;
  const int wid  = tid >> 6;
  const int lane = tid & 63;
  const int lc   = lane & 15;   // token row / expert col / D col
  const int lq   = lane >> 4;   // k-slot group / D row group
  const int by   = blockIdx.y;
  const int nch  = Hdim / KC / gridDim.y;   // 32 (128 in fallback)
  const int t0   = blockIdx.x * 64;

  const float* xp = x + (size_t)(t0 + wid * 16 + lc) * Hdim
                      + (size_t)by * nch * KC + lq * 8;
  const unsigned char* w3p = w3 + (size_t)by * nch * CH_BYTES;

  f32x4 acc[4], sum_[4], comp[4];
#pragma unroll
  for (int n = 0; n < 4; ++n) {
    acc[n] = (f32x4){0,0,0,0};
    sum_[n] = (f32x4){0,0,0,0};
    comp[n] = (f32x4){0,0,0,0};
  }

#define WAITV2() asm volatile("s_waitcnt vmcnt(2)" ::: "memory")
#define WAITV0() asm volatile("s_waitcnt vmcnt(0)" ::: "memory")
#define BAR()    __builtin_amdgcn_s_barrier()

  // stage chunk c into lds[b]: 3 x 16B per thread, linear (gload_lds-safe)
#define STAGE(c, b)                                                          \
  do {                                                                       \
    const unsigned char* gs = w3p + (size_t)(c) * CH_BYTES + tid * 16;       \
    unsigned char* ld_ = &lds[b][0] + tid * 16;                              \
    _Pragma("unroll")                                                        \
    for (int i = 0; i < 3; ++i)                                              \
      __builtin_amdgcn_global_load_lds(                                      \
          (const __attribute__((address_space(1))) unsigned int*)(gs + i*4096), \
          (__attribute__((address_space(3))) unsigned int*)(ld_ + i*4096),   \
          16, 0, 0);                                                         \
  } while (0)

#define LOADX(c, X)                                                          \
  do {                                                                       \
    X[0] = *(const float4*)(xp + (size_t)(c) * KC);                          \
    X[1] = *(const float4*)(xp + (size_t)(c) * KC + 4);                      \
  } while (0)

  // round-half-up bf16 split + v_perm pack: f = h + m + l, err ~2^-24|f|.
#define SPLIT_PAIR(f0, f1, i, AHU, AMU, ALU)                                 \
  do {                                                                       \
    u32 u0_ = __float_as_uint(f0), u1_ = __float_as_uint(f1);                \
    u32 v0_ = u0_ + 0x8000u, v1_ = u1_ + 0x8000u;                            \
    AHU[i] = __builtin_amdgcn_perm(v1_, v0_, 0x07060302u);                   \
    float r0_ = (f0) - __uint_as_float(v0_ & 0xffff0000u);                   \
    float r1_ = (f1) - __uint_as_float(v1_ & 0xffff0000u);                   \
    u32 w0_ = __float_as_uint(r0_) + 0x8000u;                                \
    u32 w1_ = __float_as_uint(r1_) + 0x8000u;                                \
    AMU[i] = __builtin_amdgcn_perm(w1_, w0_, 0x07060302u);                   \
    float s0_ = r0_ - __uint_as_float(w0_ & 0xffff0000u);                    \
    float s1_ = r1_ - __uint_as_float(w1_ & 0xffff0000u);                    \
    u32 y0_ = __float_as_uint(s0_) + 0x8000u;                                \
    u32 y1_ = __float_as_uint(s1_) + 0x8000u;                                \
    ALU[i] = __builtin_amdgcn_perm(y1_, y0_, 0x07060302u);                   \
  } while (0)

#define CONVERT(X)                                                           \
  do {                                                                       \
    V16 ah_, am_, al_;                                                       \
    SPLIT_PAIR(X[0].x, X[0].y, 0, ah_.u, am_.u, al_.u);                      \
    SPLIT_PAIR(X[0].z, X[0].w, 1, ah_.u, am_.u, al_.u);                      \
    SPLIT_PAIR(X[1].x, X[1].y, 2, ah_.u, am_.u, al_.u);                      \
    SPLIT_PAIR(X[1].z, X[1].w, 3, ah_.u, am_.u, al_.u);                      \
    Aah = ah_.s; Aam = am_.s; Aal = al_.s;                                   \
  } while (0)

  // 24 MFMAs over 2 n-pairs; within a pair 2 independent acc chains interleave.
#define MFMA_ALL(b)                                                          \
  do {                                                                       \
    const unsigned char* B_ = &lds[b][0] + lane * 16;                        \
    __builtin_amdgcn_s_setprio(1);                                           \
    _Pragma("unroll")                                                        \
    for (int g = 0; g < 2; ++g) {                                            \
      s16x8 bh0 = *(const s16x8*)(B_ + 0*4096 + (2*g)*1024);                 \
      s16x8 bh1 = *(const s16x8*)(B_ + 0*4096 + (2*g+1)*1024);               \
      s16x8 bm0 = *(const s16x8*)(B_ + 1*4096 + (2*g)*1024);                 \
      s16x8 bm1 = *(const s16x8*)(B_ + 1*4096 + (2*g+1)*1024);               \
      s16x8 bl0 = *(const s16x8*)(B_ + 2*4096 + (2*g)*1024);                 \
      s16x8 bl1 = *(const s16x8*)(B_ + 2*4096 + (2*g+1)*1024);               \
      acc[2*g]   = __builtin_amdgcn_mfma_f32_16x16x32_bf16(Aah, bh0, acc[2*g],   0,0,0); \
      acc[2*g+1] = __builtin_amdgcn_mfma_f32_16x16x32_bf16(Aah, bh1, acc[2*g+1], 0,0,0); \
      acc[2*g]   = __builtin_amdgcn_mfma_f32_16x16x32_bf16(Aah, bm0, acc[2*g],   0,0,0); \
      acc[2*g+1] = __builtin_amdgcn_mfma_f32_16x16x32_bf16(Aah, bm1, acc[2*g+1], 0,0,0); \
      acc[2*g]   = __builtin_amdgcn_mfma_f32_16x16x32_bf16(Aam, bh0, acc[2*g],   0,0,0); \
      acc[2*g+1] = __builtin_amdgcn_mfma_f32_16x16x32_bf16(Aam, bh1, acc[2*g+1], 0,0,0); \
      acc[2*g]   = __builtin_amdgcn_mfma_f32_16x16x32_bf16(Aah, bl0, acc[2*g],   0,0,0); \
      acc[2*g+1] = __builtin_amdgcn_mfma_f32_16x16x32_bf16(Aah, bl1, acc[2*g+1], 0,0,0); \
      acc[2*g]   = __builtin_amdgcn_mfma_f32_16x16x32_bf16(Aam, bm0, acc[2*g],   0,0,0); \
      acc[2*g+1] = __builtin_amdgcn_mfma_f32_16x16x32_bf16(Aam, bm1, acc[2*g+1], 0,0,0); \
      acc[2*g]   = __builtin_amdgcn_mfma_f32_16x16x32_bf16(Aal, bh0, acc[2*g],   0,0,0); \
      acc[2*g+1] = __builtin_amdgcn_mfma_f32_16x16x32_bf16(Aal, bh1, acc[2*g+1], 0,0,0); \
    }                                                                        \
    __builtin_amdgcn_s_setprio(0);                                           \
  } while (0)

  // TwoSum fold: (sum_,comp) += acc exactly; acc reset. Adds/subs only.
#define FOLD()                                                               \
  do {                                                                       \
    _Pragma("unroll")                                                        \
    for (int n = 0; n < 4; ++n)                                              \
      _Pragma("unroll")                                                      \
      for (int r = 0; r < 4; ++r) {                                          \
        float a_ = acc[n][r];                                                \
        float s_ = sum_[n][r];                                               \
        float t_ = s_ + a_;                                                  \
        float z_ = t_ - s_;                                                  \
        comp[n][r] += (s_ - (t_ - z_)) + (a_ - z_);                          \
        sum_[n][r] = t_;                                                     \
        acc[n][r] = 0.f;                                                     \
      }                                                                      \
  } while (0)

  // Steady-state iteration: stage(c+1), prefetch X(c+2), compute chunk c.
  // End queue: X(c+1)[2 old], S(c+1)[3], X(c+2)[2] -> vmcnt(2) drains the
  // L2-resident stage, leaves the newest HBM X loads in flight.
#define ITER_FULL(c, k, XCUR, XN2)                                           \
  do {                                                                       \
    STAGE((c) + 1, ((k) + 1) & 1);                                           \
    LOADX((c) + 2, XN2);                                                     \
    CONVERT(XCUR);                                                           \
    __builtin_amdgcn_sched_barrier(0);                                       \
    MFMA_ALL((k) & 1);                                                       \
    WAITV2();                                                                \
    BAR();                                                                   \
  } while (0)

  float4 X0[2], X1[2], X2[2], X3[2];
  s16x8 Aah, Aam, Aal;

  // prologue: stage chunk 0, prefetch X(0), X(1); drain stage only.
  STAGE(0, 0);
  LOADX(0, X0);
  LOADX(1, X1);
  asm volatile("s_waitcnt vmcnt(4)" ::: "memory");
  BAR();

#pragma unroll 1
  for (int c = 0; c + 4 < nch; c += 4) {
    ITER_FULL(c + 0, 0, X0, X2);
    ITER_FULL(c + 1, 1, X1, X3);
    ITER_FULL(c + 2, 2, X2, X0);
    ITER_FULL(c + 3, 3, X3, X1);
    FOLD();
  }
  {  // tail group: chunks nch-4 .. nch-1 (nch % 4 == 0, nch >= 8)
    const int c = nch - 4;
    ITER_FULL(c + 0, 0, X0, X2);
    ITER_FULL(c + 1, 1, X1, X3);
    // chunk nch-2: stage last chunk, no X prefetch, full drain
    STAGE(c + 3, 1);
    CONVERT(X2);
    __builtin_amdgcn_sched_barrier(0);
    MFMA_ALL(0);
    WAITV0();
    BAR();
    // chunk nch-1: compute only
    CONVERT(X3);
    MFMA_ALL(1);
    FOLD();
  }

  if (gridDim.y != 1) {
    // ---- partial mode: write (hi, lo) planes ----
#pragma unroll
    for (int n = 0; n < 4; ++n)
#pragma unroll
      for (int r = 0; r < 4; ++r) {
        const int tok = t0 + wid * 16 + lq * 4 + r;
        const size_t o = ((size_t)by * T + tok) * E_DIM + n * 16 + lc;
        hi_p[o] = sum_[n][r];
        lo_p[o] = comp[n][r];
      }
    return;
  }

  // ---- fused epilogue (fallback, gridDim.y==1) ----
  float bias_v[4];
#pragma unroll
  for (int n = 0; n < 4; ++n) bias_v[n] = bias[n * 16 + lc];

  float pr[4][4], bi[4][4];
#pragma unroll
  for (int n = 0; n < 4; ++n)
#pragma unroll
    for (int r = 0; r < 4; ++r) {
      float logit = sum_[n][r] + comp[n][r];
      float p = 1.0f / (1.0f + expf(-logit));
      pr[n][r] = p;
      bi[n][r] = p + bias_v[n];
    }
#pragma unroll
  for (int r = 0; r < 4; ++r) {
    float v0 = bi[0][r], v1 = bi[1][r], v2 = bi[2][r], v3 = bi[3][r];
    float p0 = pr[0][r], p1 = pr[1][r], p2 = pr[2][r], p3 = pr[3][r];
    float sum = 0.f, selp = 0.f;
    int seli = 0;
#pragma unroll
    for (int k = 0; k < 8; ++k) {
      float bv = v0; int bn = 0; float bp = p0;
      if (v1 > bv) { bv = v1; bn = 1; bp = p1; }
      if (v2 > bv) { bv = v2; bn = 2; bp = p2; }
      if (v3 > bv) { bv = v3; bn = 3; bp = p3; }
      int be = bn * 16 + lc;
#pragma unroll
      for (int off = 8; off >= 1; off >>= 1) {
        float ov = __shfl_xor(bv, off);
        float op = __shfl_xor(bp, off);
        int   oe = __shfl_xor(be, off);
        if (ov > bv || (ov == bv && oe < be)) { bv = ov; bp = op; be = oe; }
      }
      sum += bp;
      if (lc == k) { selp = bp; seli = be; }
      if (lc == (be & 15)) {
        int gsel = be >> 4;
        if      (gsel == 0) v0 = -1e30f;
        else if (gsel == 1) v1 = -1e30f;
        else if (gsel == 2) v2 = -1e30f;
        else                v3 = -1e30f;
      }
    }
    if (lc < 8) {
      const int tok = t0 + wid * 16 + lq * 4 + r;
      outw[(size_t)tok * 8 + lc] = selp * 2.5f / (sum + 1e-20f);
      outi[(size_t)tok * 8 + lc] = (float)seli;
    }
  }
}

// ---- kernel T: combine partials (TwoSum) + sigmoid + top-8 ----
__global__ __launch_bounds__(256) void router_topk(
    const float* __restrict__ hi_p, const float* __restrict__ lo_p,
    const float* __restrict__ bias, float* __restrict__ outw,
    float* __restrict__ outi, int T)
{
  const int lane = threadIdx.x & 63;
  const int t = blockIdx.x * 4 + (threadIdx.x >> 6);
  if (t >= T) return;

  float s = 0.f, c = 0.f, losum = 0.f;
#pragma unroll
  for (int p = 0; p < NPART; ++p) {
    const size_t o = ((size_t)p * T + t) * E_DIM + lane;
    float a = hi_p[o];
    float tt = s + a;
    float z = tt - s;
    c += (s - (tt - z)) + (a - z);
    s = tt;
    losum += lo_p[o];
  }
  const float logit = s + (c + losum);

  const float prob = 1.0f / (1.0f + expf(-logit));
  float v = prob + bias[lane];

  float sum = 0.f, selw = 0.f;
  int seli = 0;
#pragma unroll
  for (int k = 0; k < 8; ++k) {
    float rv = v;
    int   ri = lane;
#pragma unroll
    for (int off = 32; off > 0; off >>= 1) {
      float ov = __shfl_xor(rv, off);
      int   oi = __shfl_xor(ri, off);
      if (ov > rv || (ov == rv && oi < ri)) { rv = ov; ri = oi; }
    }
    float pwin = __shfl(prob, ri);
    sum += pwin;
    if (lane == k)  { selw = pwin; seli = ri; }
    if (lane == ri) v = -INFINITY;
  }

  if (lane < 8) {
    float scale = 2.5f / (sum + 1e-20f);
    outw[(size_t)t * 8 + lane] = selw * scale;
    outi[(size_t)t * 8 + lane] = (float)seli;
  }
}

extern "C" void kernel_launch(void* const* d_in, const int* in_sizes, int n_in,
                              void* d_out, int out_size, void* d_ws, size_t ws_size,
                              hipStream_t stream) {
  const float* x    = (const float*)d_in[0];
  const float* w    = (const float*)d_in[1];
  const float* bias = (const float*)d_in[2];

  const int E    = in_sizes[2];          // 64
  const int Hdim = in_sizes[1] / E;      // 4096
  const int T    = in_sizes[0] / Hdim;   // 16384

  unsigned char* ws = (unsigned char*)d_ws;
  unsigned char* w3 = ws;                      // 1.5 MB
  float* hi_p = (float*)(ws + HI_OFF);         // NPART*T*64 f32 = 16 MB
  float* lo_p = hi_p + (size_t)NPART * T * E_DIM;

  const size_t need = (size_t)HI_OFF + (size_t)2 * NPART * T * E_DIM * sizeof(float);
  const int nparts = (ws_size >= need) ? NPART : 1;

  const int nElemGroups = E * Hdim / 16;
  split_w<<<(nElemGroups + 255) / 256, 256, 0, stream>>>(w, w3, Hdim);

  float* outw = (float*)d_out;
  float* outi = outw + (size_t)T * 8;

  dim3 gridG(T / 64, nparts);
  router_mfma<<<gridG, 256, 0, stream>>>(x, w3, bias, outw, outi, hi_p, lo_p, T, Hdim);

  if (nparts != 1) {
    router_topk<<<(T + 3) / 4, 256, 0, stream>>>(hi_p, lo_p, bias, outw, outi, T);
  }
}

// Round 9
// 109.898 us; speedup vs baseline: 1.1481x; 1.0216x over previous
//
#include <hip/hip_runtime.h>
#include <cmath>

// MoE router via 3-way bf16-split MFMA emulation of fp32 GEMM, compensated
// (TwoSum) accumulation. R9: fix the in-order vmcnt queue. R8's vmcnt(2)
// still force-drained X(c+1) (older than the stage in the queue). Now:
// triple-buffered LDS, stage TWO chunks ahead, so the per-iter drain
// vmcnt(5) retires exactly [S(c+1), X(c+1)] (both >=1.5 iters old) and
// leaves [S(c+2), X(c+2)] in flight across the barrier. launch_bounds
// (256,4) + trimmed reg budget (X depth-2 WAR reuse, per-g B transients)
// -> 16 waves/CU. Partials as float2 (hi,lo) [t][part][e].
//
// logits[T,64] = x[T,4096] @ w[64,4096]^T, sigmoid, top-8 on prob+bias,
// weights = p/sum*2.5. Outputs: weights[T,8] f32, then indices[T,8] as f32.

typedef float f32x4 __attribute__((ext_vector_type(4)));
typedef short s16x8 __attribute__((ext_vector_type(8)));
typedef unsigned int u32;
typedef u32 u32x4 __attribute__((ext_vector_type(4)));

#define E_DIM 64
#define KC 32
#define CH_BYTES 12288   // 3 splits * 4 ntiles * 64 lanes * 16B
#define NPART 4
#define HI_OFF (2u << 20)   // partial pairs start at 2 MB (w3 is 1.5 MB)

union V16 { u32x4 u; s16x8 s; };

__device__ __forceinline__ unsigned short f2bf(float f) {
  unsigned u = __float_as_uint(f);
  u += 0x7fffu + ((u >> 16) & 1u);   // round-to-nearest-even
  return (unsigned short)(u >> 16);
}
__device__ __forceinline__ float bf2f(unsigned short s) {
  return __uint_as_float(((unsigned)s) << 16);
}

// ---- kernel W: split w into 3 bf16 planes, in per-lane B-fragment layout ----
// w3[c][s][n][lane]*16B ; lane holds expert e=n*16+(lane&15),
// k = c*32 + (lane>>4)*8 + j  (j=0..7 within the 16B slot).
__global__ __launch_bounds__(256) void split_w(
    const float* __restrict__ w, unsigned char* __restrict__ w3, int Hdim)
{
  const int kpr = Hdim >> 4;                      // 16-elem k-groups per row
  const int g = blockIdx.x * 256 + threadIdx.x;
  const int e = g / kpr;
  const int k0 = (g - e * kpr) * 16;
  if (e >= E_DIM) return;

  const float* src = w + (size_t)e * Hdim + k0;
  float f[16];
#pragma unroll
  for (int i = 0; i < 4; ++i) {
    float4 v = *(const float4*)(src + i * 4);
    f[i*4+0] = v.x; f[i*4+1] = v.y; f[i*4+2] = v.z; f[i*4+3] = v.w;
  }
  unsigned short hs[16], ms[16], ls[16];
#pragma unroll
  for (int i = 0; i < 16; ++i) {
    unsigned short h = f2bf(f[i]);
    float r1 = f[i] - bf2f(h);
    unsigned short m = f2bf(r1);
    float r2 = r1 - bf2f(m);
    hs[i] = h; ms[i] = m; ls[i] = f2bf(r2);
  }
  const int c  = k0 >> 5;                          // chunk of 32 k
  const int n  = e >> 4;                           // n-tile
  const int la = (e & 15) + (((k0 & 31) >> 3) << 4);  // lane of first 8 elems
  unsigned char* base = w3 + (size_t)c * CH_BYTES + n * 1024;

#define STORE_SPLIT(arr, s)                                              \
  do {                                                                   \
    s16x8 pa, pb;                                                        \
    _Pragma("unroll")                                                    \
    for (int j = 0; j < 8; ++j) { pa[j] = (short)arr[j]; pb[j] = (short)arr[8+j]; } \
    *(s16x8*)(base + (s)*4096 + la * 16)        = pa;                    \
    *(s16x8*)(base + (s)*4096 + (la + 16) * 16) = pb;                    \
  } while (0)

  STORE_SPLIT(hs, 0);
  STORE_SPLIT(ms, 1);
  STORE_SPLIT(ls, 2);
#undef STORE_SPLIT
}

// ---- kernel G: triple-buffered LDS, stage-2-ahead, counted-vmcnt GEMM ----
__global__ __launch_bounds__(256, 4) void router_mfma(
    const float* __restrict__ x, const unsigned char* __restrict__ w3,
    const float* __restrict__ bias, float* __restrict__ outw,
    float* __restrict__ outi, float2* __restrict__ pp,
    int T, int Hdim)
{
  __shared__ __align__(16) unsigned char lds[3 * CH_BYTES];  // 36 KB

  const int tid  = threadIdx.x;
  const int wid  = tid >> 6;
  const int lane = tid & 63;
  const int lc   = lane & 15;   // token row / expert col / D col
  const int lq   = lane >> 4;   // k-slot group / D row group
  const int by   = blockIdx.y;
  const int nch  = Hdim / KC / gridDim.y;   // 32 (128 in fallback)
  const int t0   = blockIdx.x * 64;

  const float* xp = x + (size_t)(t0 + wid * 16 + lc) * Hdim
                      + (size_t)by * nch * KC + lq * 8;
  const unsigned char* w3p = w3 + (size_t)by * nch * CH_BYTES;

  f32x4 acc[4], sum_[4], comp[4];
#pragma unroll
  for (int n = 0; n < 4; ++n) {
    acc[n] = (f32x4){0,0,0,0};
    sum_[n] = (f32x4){0,0,0,0};
    comp[n] = (f32x4){0,0,0,0};
  }

#define SB()     __builtin_amdgcn_sched_barrier(0)
#define WAITV5() asm volatile("s_waitcnt vmcnt(5)" ::: "memory")
#define WAITV0() asm volatile("s_waitcnt vmcnt(0)" ::: "memory")
#define BAR()    __builtin_amdgcn_s_barrier()

  // stage chunk c into lds+so: 3 x 16B per thread, linear (gload_lds-safe)
#define STAGE(c, so)                                                         \
  do {                                                                       \
    const unsigned char* gs = w3p + (size_t)(c) * CH_BYTES + tid * 16;       \
    unsigned char* ld_ = &lds[0] + (so) + tid * 16;                          \
    _Pragma("unroll")                                                        \
    for (int i = 0; i < 3; ++i)                                              \
      __builtin_amdgcn_global_load_lds(                                      \
          (const __attribute__((address_space(1))) unsigned int*)(gs + i*4096), \
          (__attribute__((address_space(3))) unsigned int*)(ld_ + i*4096),   \
          16, 0, 0);                                                         \
  } while (0)

#define LOADX(c, X)                                                          \
  do {                                                                       \
    X[0] = *(const float4*)(xp + (size_t)(c) * KC);                          \
    X[1] = *(const float4*)(xp + (size_t)(c) * KC + 4);                      \
  } while (0)

  // round-half-up bf16 split + v_perm pack: f = h + m + l, err ~2^-24|f|.
#define SPLIT_PAIR(f0, f1, i, AHU, AMU, ALU)                                 \
  do {                                                                       \
    u32 u0_ = __float_as_uint(f0), u1_ = __float_as_uint(f1);                \
    u32 v0_ = u0_ + 0x8000u, v1_ = u1_ + 0x8000u;                            \
    AHU[i] = __builtin_amdgcn_perm(v1_, v0_, 0x07060302u);                   \
    float r0_ = (f0) - __uint_as_float(v0_ & 0xffff0000u);                   \
    float r1_ = (f1) - __uint_as_float(v1_ & 0xffff0000u);                   \
    u32 w0_ = __float_as_uint(r0_) + 0x8000u;                                \
    u32 w1_ = __float_as_uint(r1_) + 0x8000u;                                \
    AMU[i] = __builtin_amdgcn_perm(w1_, w0_, 0x07060302u);                   \
    float s0_ = r0_ - __uint_as_float(w0_ & 0xffff0000u);                    \
    float s1_ = r1_ - __uint_as_float(w1_ & 0xffff0000u);                    \
    u32 y0_ = __float_as_uint(s0_) + 0x8000u;                                \
    u32 y1_ = __float_as_uint(s1_) + 0x8000u;                                \
    ALU[i] = __builtin_amdgcn_perm(y1_, y0_, 0x07060302u);                   \
  } while (0)

#define CONVERT(X)                                                           \
  do {                                                                       \
    V16 ah_, am_, al_;                                                       \
    SPLIT_PAIR(X[0].x, X[0].y, 0, ah_.u, am_.u, al_.u);                      \
    SPLIT_PAIR(X[0].z, X[0].w, 1, ah_.u, am_.u, al_.u);                      \
    SPLIT_PAIR(X[1].x, X[1].y, 2, ah_.u, am_.u, al_.u);                      \
    SPLIT_PAIR(X[1].z, X[1].w, 3, ah_.u, am_.u, al_.u);                      \
    Aah = ah_.s; Aam = am_.s; Aal = al_.s;                                   \
  } while (0)

  // 24 MFMAs; B loaded per n-pair (6 live transients) to cap VGPR.
#define MFMA_ALL(ro)                                                         \
  do {                                                                       \
    const unsigned char* B_ = &lds[0] + (ro) + lane * 16;                    \
    __builtin_amdgcn_s_setprio(1);                                           \
    _Pragma("unroll")                                                        \
    for (int g = 0; g < 2; ++g) {                                            \
      s16x8 bh0 = *(const s16x8*)(B_ + 0*4096 + (2*g)*1024);                 \
      s16x8 bh1 = *(const s16x8*)(B_ + 0*4096 + (2*g+1)*1024);               \
      s16x8 bm0 = *(const s16x8*)(B_ + 1*4096 + (2*g)*1024);                 \
      s16x8 bm1 = *(const s16x8*)(B_ + 1*4096 + (2*g+1)*1024);               \
      s16x8 bl0 = *(const s16x8*)(B_ + 2*4096 + (2*g)*1024);                 \
      s16x8 bl1 = *(const s16x8*)(B_ + 2*4096 + (2*g+1)*1024);               \
      acc[2*g]   = __builtin_amdgcn_mfma_f32_16x16x32_bf16(Aah, bh0, acc[2*g],   0,0,0); \
      acc[2*g+1] = __builtin_amdgcn_mfma_f32_16x16x32_bf16(Aah, bh1, acc[2*g+1], 0,0,0); \
      acc[2*g]   = __builtin_amdgcn_mfma_f32_16x16x32_bf16(Aah, bm0, acc[2*g],   0,0,0); \
      acc[2*g+1] = __builtin_amdgcn_mfma_f32_16x16x32_bf16(Aah, bm1, acc[2*g+1], 0,0,0); \
      acc[2*g]   = __builtin_amdgcn_mfma_f32_16x16x32_bf16(Aam, bh0, acc[2*g],   0,0,0); \
      acc[2*g+1] = __builtin_amdgcn_mfma_f32_16x16x32_bf16(Aam, bh1, acc[2*g+1], 0,0,0); \
      acc[2*g]   = __builtin_amdgcn_mfma_f32_16x16x32_bf16(Aah, bl0, acc[2*g],   0,0,0); \
      acc[2*g+1] = __builtin_amdgcn_mfma_f32_16x16x32_bf16(Aah, bl1, acc[2*g+1], 0,0,0); \
      acc[2*g]   = __builtin_amdgcn_mfma_f32_16x16x32_bf16(Aam, bm0, acc[2*g],   0,0,0); \
      acc[2*g+1] = __builtin_amdgcn_mfma_f32_16x16x32_bf16(Aam, bm1, acc[2*g+1], 0,0,0); \
      acc[2*g]   = __builtin_amdgcn_mfma_f32_16x16x32_bf16(Aal, bh0, acc[2*g],   0,0,0); \
      acc[2*g+1] = __builtin_amdgcn_mfma_f32_16x16x32_bf16(Aal, bh1, acc[2*g+1], 0,0,0); \
    }                                                                        \
    __builtin_amdgcn_s_setprio(0);                                           \
  } while (0)

  // TwoSum fold: (sum_,comp) += acc exactly; acc reset. Adds/subs only.
#define FOLD()                                                               \
  do {                                                                       \
    _Pragma("unroll")                                                        \
    for (int n = 0; n < 4; ++n)                                              \
      _Pragma("unroll")                                                      \
      for (int r = 0; r < 4; ++r) {                                          \
        float a_ = acc[n][r];                                                \
        float s_ = sum_[n][r];                                               \
        float t_ = s_ + a_;                                                  \
        float z_ = t_ - s_;                                                  \
        comp[n][r] += (s_ - (t_ - z_)) + (a_ - z_);                          \
        sum_[n][r] = t_;                                                     \
        acc[n][r] = 0.f;                                                     \
      }                                                                      \
  } while (0)

  // Steady-state: entering iter c, queue = [S(c+1), X(c+1)].
  // Issue S(c+2); consume X(c); re-issue X(c+2) into freed regs; MFMA;
  // vmcnt(5) retires exactly S(c+1)+X(c+1), leaves [S(c+2), X(c+2)].
#define ITER(c, ro, so, XBUF)                                                \
  do {                                                                       \
    STAGE((c) + 2, so);                                                      \
    CONVERT(XBUF);                                                           \
    LOADX((c) + 2, XBUF);                                                    \
    SB();                                                                    \
    MFMA_ALL(ro);                                                            \
    WAITV5();                                                                \
    BAR();                                                                   \
  } while (0)

  float4 XA[2], XB[2];
  s16x8 Aah, Aam, Aal;

  int ro0 = 0, ro1 = CH_BYTES, ro2 = 2 * CH_BYTES;

  // prologue: S0, S1, X0, X1 (order matters for the in-order queue)
  STAGE(0, ro0);
  STAGE(1, ro1);
  LOADX(0, XA);
  LOADX(1, XB);

#pragma unroll 1
  for (int c = 0; c < nch - 4; c += 4) {
    ITER(c + 0, ro0, ro2, XA);
    ITER(c + 1, ro1, ro0, XB);
    ITER(c + 2, ro2, ro1, XA);
    ITER(c + 3, ro0, ro2, XB);
    FOLD();
    int t_ = ro0; ro0 = ro1; ro1 = ro2; ro2 = t_;
  }
  // last 4 chunks: 2 full iters (stage nch-2, nch-1), then 2 compute-only
  ITER(nch - 4, ro0, ro2, XA);
  ITER(nch - 3, ro1, ro0, XB);
  {  // chunk nch-2: queue entering = [S(nch-1), X(nch-1)]
    CONVERT(XA);
    SB();
    MFMA_ALL(ro2);
    WAITV0();
    BAR();
    // chunk nch-1: everything drained
    CONVERT(XB);
    SB();
    MFMA_ALL(ro0);
    FOLD();
  }

  if (gridDim.y != 1) {
    // ---- partial mode: write (hi, lo) float2 pairs, [t][part][e] ----
#pragma unroll
    for (int n = 0; n < 4; ++n)
#pragma unroll
      for (int r = 0; r < 4; ++r) {
        const int tok = t0 + wid * 16 + lq * 4 + r;
        const size_t o = ((size_t)tok * NPART + by) * E_DIM + n * 16 + lc;
        pp[o] = make_float2(sum_[n][r], comp[n][r]);
      }
    return;
  }

  // ---- fused epilogue (fallback, gridDim.y==1) ----
  float bias_v[4];
#pragma unroll
  for (int n = 0; n < 4; ++n) bias_v[n] = bias[n * 16 + lc];

  float pr[4][4], bi[4][4];
#pragma unroll
  for (int n = 0; n < 4; ++n)
#pragma unroll
    for (int r = 0; r < 4; ++r) {
      float logit = sum_[n][r] + comp[n][r];
      float p = 1.0f / (1.0f + expf(-logit));
      pr[n][r] = p;
      bi[n][r] = p + bias_v[n];
    }
#pragma unroll
  for (int r = 0; r < 4; ++r) {
    float v0 = bi[0][r], v1 = bi[1][r], v2 = bi[2][r], v3 = bi[3][r];
    float p0 = pr[0][r], p1 = pr[1][r], p2 = pr[2][r], p3 = pr[3][r];
    float sum = 0.f, selp = 0.f;
    int seli = 0;
#pragma unroll
    for (int k = 0; k < 8; ++k) {
      float bv = v0; int bn = 0; float bp = p0;
      if (v1 > bv) { bv = v1; bn = 1; bp = p1; }
      if (v2 > bv) { bv = v2; bn = 2; bp = p2; }
      if (v3 > bv) { bv = v3; bn = 3; bp = p3; }
      int be = bn * 16 + lc;
#pragma unroll
      for (int off = 8; off >= 1; off >>= 1) {
        float ov = __shfl_xor(bv, off);
        float op = __shfl_xor(bp, off);
        int   oe = __shfl_xor(be, off);
        if (ov > bv || (ov == bv && oe < be)) { bv = ov; bp = op; be = oe; }
      }
      sum += bp;
      if (lc == k) { selp = bp; seli = be; }
      if (lc == (be & 15)) {
        int gsel = be >> 4;
        if      (gsel == 0) v0 = -1e30f;
        else if (gsel == 1) v1 = -1e30f;
        else if (gsel == 2) v2 = -1e30f;
        else                v3 = -1e30f;
      }
    }
    if (lc < 8) {
      const int tok = t0 + wid * 16 + lq * 4 + r;
      outw[(size_t)tok * 8 + lc] = selp * 2.5f / (sum + 1e-20f);
      outi[(size_t)tok * 8 + lc] = (float)seli;
    }
  }
}

// ---- kernel T: combine (hi,lo) pairs (TwoSum) + sigmoid + top-8 ----
__global__ __launch_bounds__(256) void router_topk(
    const float2* __restrict__ pp, const float* __restrict__ bias,
    float* __restrict__ outw, float* __restrict__ outi, int T)
{
  const int lane = threadIdx.x & 63;
  const int t = blockIdx.x * 4 + (threadIdx.x >> 6);
  if (t >= T) return;

  float s = 0.f, c = 0.f, losum = 0.f;
#pragma unroll
  for (int p = 0; p < NPART; ++p) {
    const float2 v = pp[((size_t)t * NPART + p) * E_DIM + lane];
    float a = v.x;
    float tt = s + a;
    float z = tt - s;
    c += (s - (tt - z)) + (a - z);
    s = tt;
    losum += v.y;
  }
  const float logit = s + (c + losum);

  const float prob = 1.0f / (1.0f + expf(-logit));
  float v = prob + bias[lane];

  float sum = 0.f, selw = 0.f;
  int seli = 0;
#pragma unroll
  for (int k = 0; k < 8; ++k) {
    float rv = v;
    int   ri = lane;
#pragma unroll
    for (int off = 32; off > 0; off >>= 1) {
      float ov = __shfl_xor(rv, off);
      int   oi = __shfl_xor(ri, off);
      if (ov > rv || (ov == rv && oi < ri)) { rv = ov; ri = oi; }
    }
    float pwin = __shfl(prob, ri);
    sum += pwin;
    if (lane == k)  { selw = pwin; seli = ri; }
    if (lane == ri) v = -INFINITY;
  }

  if (lane < 8) {
    float scale = 2.5f / (sum + 1e-20f);
    outw[(size_t)t * 8 + lane] = selw * scale;
    outi[(size_t)t * 8 + lane] = (float)seli;
  }
}

extern "C" void kernel_launch(void* const* d_in, const int* in_sizes, int n_in,
                              void* d_out, int out_size, void* d_ws, size_t ws_size,
                              hipStream_t stream) {
  const float* x    = (const float*)d_in[0];
  const float* w    = (const float*)d_in[1];
  const float* bias = (const float*)d_in[2];

  const int E    = in_sizes[2];          // 64
  const int Hdim = in_sizes[1] / E;      // 4096
  const int T    = in_sizes[0] / Hdim;   // 16384

  unsigned char* ws = (unsigned char*)d_ws;
  unsigned char* w3 = ws;                      // 1.5 MB
  float2* pp = (float2*)(ws + HI_OFF);         // NPART*T*64 float2 = 32 MB

  const size_t need = (size_t)HI_OFF + (size_t)NPART * T * E_DIM * sizeof(float2);
  const int nparts = (ws_size >= need) ? NPART : 1;

  const int nElemGroups = E * Hdim / 16;
  split_w<<<(nElemGroups + 255) / 256, 256, 0, stream>>>(w, w3, Hdim);

  float* outw = (float*)d_out;
  float* outi = outw + (size_t)T * 8;

  dim3 gridG(T / 64, nparts);
  router_mfma<<<gridG, 256, 0, stream>>>(x, w3, bias, outw, outi, pp, T, Hdim);

  if (nparts != 1) {
    router_topk<<<(T + 3) / 4, 256, 0, stream>>>(pp, bias, outw, outi, T);
  }
}